// Round 6
// baseline (168.338 us; speedup 1.0000x reference)
//
#include <hip/hip_runtime.h>
#include <hip/hip_bf16.h>

typedef __attribute__((ext_vector_type(8))) short short8;
typedef __attribute__((ext_vector_type(4))) float float4v;

#define LOG2E 1.44269504088896340736f

typedef __attribute__((address_space(1))) const unsigned int gu32;
typedef __attribute__((address_space(3))) unsigned int su32;

__device__ __forceinline__ unsigned short f2bf(float f) {
    unsigned int u = __float_as_uint(f);
    unsigned int r = (u + 0x7fffu + ((u >> 16) & 1u)) >> 16;  // RNE
    return (unsigned short)r;
}

// ---------------------------------------------------------------------------
// Kernel 1: convert Wk|Wq|Wv (fp32) -> combined bf16 Wb[192][1024]
// ---------------------------------------------------------------------------
__global__ void wconv_kernel(const float* __restrict__ Wk, const float* __restrict__ Wq,
                             const float* __restrict__ Wv, unsigned short* __restrict__ Wb) {
    int i = blockIdx.x * 256 + threadIdx.x;
    if (i >= 192 * 1024) return;
    float v;
    if (i < 65536)       v = Wk[i];
    else if (i < 131072) v = Wq[i - 65536];
    else                 v = Wv[i - 131072];
    Wb[i] = f2bf(v);
}

// ---------------------------------------------------------------------------
// Kernel 2: projection GEMM — REVERTED to R13 (best measured: ~40us, total
// 149.97). Five structural variants (R11-R16: syncthreads / counted vmcnt /
// barrier-free / 8-wave / no-DMA) all landed 40-50us with every pipe idle;
// proj micro-structure is exhausted. This round pivots to attn.
// ---------------------------------------------------------------------------
__global__ __launch_bounds__(256) void proj_kernel(
    const float* __restrict__ x, const unsigned short* __restrict__ Wb,
    unsigned short* __restrict__ qs, unsigned short* __restrict__ ks,
    unsigned short* __restrict__ vT) {
    __shared__ unsigned short Bl[2][12288];  // 2 x 192 rows x 64 ushort, 48 KB

    const int tid  = threadIdx.x;
    const int lane = tid & 63;
    const int wave = tid >> 6;
    const int rg   = wave & 1;   // row group
    const int g    = wave >> 1;  // n-tile group
    const int quad = lane >> 4;
    const int l16  = lane & 15;
    const int t0   = blockIdx.x * 32;

    // async staging geometry: wave covers regions wave*6..+5; region = 8 rows
    // of 128 B; lane l -> (row l>>3, LDS chunk l&7), source chunk (l&7)^(l>>3)
    const int srow_in = lane >> 3;                 // 0..7
    const int csrc    = (lane & 7) ^ srow_in;      // XOR swizzle source chunk

    const int rowA = t0 + rg * 16 + l16;
    const float* xr = x + (size_t)rowA * 1024;

    float4v acc[6];
#pragma unroll
    for (int n = 0; n < 6; n++) acc[n] = (float4v){0.f, 0.f, 0.f, 0.f};

#define STAGE_B(BUF, KN)                                                          \
    {                                                                             \
        _Pragma("unroll")                                                         \
        for (int i = 0; i < 6; i++) {                                             \
            const int region = wave * 6 + i;                                      \
            const int rowg   = region * 8 + srow_in;                              \
            const unsigned short* src = Wb + (size_t)rowg * 1024 + (KN) + csrc * 8; \
            __builtin_amdgcn_global_load_lds((gu32*)src,                          \
                                             (su32*)&Bl[BUF][region * 512],       \
                                             16, 0, 0);                           \
        }                                                                         \
    }

    // prologue: stage tile 0; A-register prefetch tiles 0 and 1 (2-deep)
    STAGE_B(0, 0)
    float4v a0[4], a1[4];
    a0[0] = *(const float4v*)(xr + quad * 8);
    a0[1] = *(const float4v*)(xr + quad * 8 + 4);
    a0[2] = *(const float4v*)(xr + 32 + quad * 8);
    a0[3] = *(const float4v*)(xr + 32 + quad * 8 + 4);
    a1[0] = *(const float4v*)(xr + 64 + quad * 8);
    a1[1] = *(const float4v*)(xr + 64 + quad * 8 + 4);
    a1[2] = *(const float4v*)(xr + 96 + quad * 8);
    a1[3] = *(const float4v*)(xr + 96 + quad * 8 + 4);

    const int swz = l16 & 7;

#pragma unroll
    for (int kt = 0; kt < 16; kt++) {
        __builtin_amdgcn_sched_barrier(0);
        // wait: stage(kt) + A(kt) landed; newest 4 = A(kt+1) may keep flying.
        if (kt < 15) {
            asm volatile("s_waitcnt vmcnt(4)" ::: "memory");
        } else {
            asm volatile("s_waitcnt vmcnt(0)" ::: "memory");
        }
        __builtin_amdgcn_s_barrier();
        if (kt < 15) STAGE_B((kt + 1) & 1, (kt + 1) * 64)
        asm volatile("" ::: "memory");  // pin issue order: stages before A-loads
        float4v an[4];
        if (kt < 14) {
            const int kn2 = (kt + 2) * 64;
            an[0] = *(const float4v*)(xr + kn2 + quad * 8);
            an[1] = *(const float4v*)(xr + kn2 + quad * 8 + 4);
            an[2] = *(const float4v*)(xr + kn2 + 32 + quad * 8);
            an[3] = *(const float4v*)(xr + kn2 + 32 + quad * 8 + 4);
        }
        const unsigned short* Bc = Bl[kt & 1];
#pragma unroll
        for (int kc = 0; kc < 2; kc++) {
            short8 af;
#pragma unroll
            for (int j = 0; j < 4; j++) af[j] = (short)f2bf(a0[kc * 2][j]);
#pragma unroll
            for (int j = 0; j < 4; j++) af[4 + j] = (short)f2bf(a0[kc * 2 + 1][j]);
#pragma unroll
            for (int n = 0; n < 6; n++) {
                const int row  = (g * 6 + n) * 16 + l16;
                const int coff = ((kc * 4 + quad) ^ swz) * 8;
                const short8 bf = *(const short8*)&Bc[row * 64 + coff];
                acc[n] = __builtin_amdgcn_mfma_f32_16x16x32_bf16(af, bf, acc[n], 0, 0, 0);
            }
        }
        if (kt < 14) {
#pragma unroll
            for (int i = 0; i < 4; i++) { a0[i] = a1[i]; a1[i] = an[i]; }
        } else if (kt < 15) {
#pragma unroll
            for (int i = 0; i < 4; i++) a0[i] = a1[i];
        }
    }
#undef STAGE_B

    // Epilogue. C layout: row = quad*4 + r, col = l16.
    const int rowD = t0 + rg * 16 + quad * 4;
#pragma unroll
    for (int r = 0; r < 4; r++) {
        const int t = rowD + r;
        const int b = t >> 11, tt = t & 2047;
        if (g == 0) {
#pragma unroll
            for (int n = 0; n < 4; n++)
                ks[(size_t)t * 64 + n * 16 + l16] = f2bf(acc[n][r]);
#pragma unroll
            for (int n = 4; n < 6; n++)
                qs[(size_t)t * 64 + (n - 4) * 16 + l16] = f2bf(acc[n][r] * 0.125f);
        } else {
#pragma unroll
            for (int n = 0; n < 2; n++)
                qs[(size_t)t * 64 + (n + 2) * 16 + l16] = f2bf(acc[n][r] * 0.125f);
#pragma unroll
            for (int n = 2; n < 6; n++)
                vT[(size_t)b * 131072 + (size_t)((n - 2) * 16 + l16) * 2048 + tt] = f2bf(acc[n][r]);
        }
    }
}

// ---------------------------------------------------------------------------
// Kernel 3: causal attention v4 — NO K/V LDS STAGING (guide common-mistake
// #7). The old Kl/Vl staging had ZERO cross-wave sharing: wave w only read
// rows kbase=w*64..+63 of Kl and cols w*64..+63 of Vl — every staged byte
// consumed by exactly the wave that could have loaded it directly. K,V per
// batch = 256 KB each -> L2-resident; staging + 2 barriers/super-iter +
// idle-wave staging was pure overhead AND its 71 KB LDS capped occupancy
// at 2 blocks/CU. Now: K/V fragments load short8-direct from global
// (address = staged-path composition: key0+kbase+kt*16+l16 = jt*64+...;
// clamps unnecessary since jt*64+63 <= 2047). Per-wave K-loop is
// BARRIER-FREE (P[wave] is wave-private; for jt=wave; jt<nkb; jt+=4).
// LDS 80 KB -> 27 KB (P + dedicated Of + Ll): 4 blocks/CU all resident,
// waves/SIMD 2 -> 4. Only the final merge keeps its 2 syncthreads.
// ---------------------------------------------------------------------------
__global__ __launch_bounds__(256, 4) void attn_kernel(
    const unsigned short* __restrict__ qs, const unsigned short* __restrict__ ks,
    const unsigned short* __restrict__ vT, float* __restrict__ out) {
    __shared__ unsigned short P[4][16 * 72];
    __shared__ float Ll[4][16];
    __shared__ float Of[4][16][68];

    const int tid  = threadIdx.x;
    const int lane = tid & 63;
    const int wave = tid >> 6;
    const int quad = lane >> 4;
    const int l16  = lane & 15;
    const int bx   = blockIdx.x;
    const int b    = bx & 7;
    const int i    = bx >> 3;
    const int qt   = (i & 1) ? (127 - (i >> 1)) : (i >> 1);
    const int t0   = qt * 16;

    const unsigned short* qb = qs + (size_t)b * 131072;
    const unsigned short* kb = ks + (size_t)b * 131072;
    const unsigned short* vb = vT + (size_t)b * 131072;

    const int qrow = t0 + l16;
    const short8 qf0 = *(const short8*)(qb + (size_t)qrow * 64 + quad * 8);
    const short8 qf1 = *(const short8*)(qb + (size_t)qrow * 64 + 32 + quad * 8);

    float4v o[4];
#pragma unroll
    for (int ot = 0; ot < 4; ot++) o[ot] = (float4v){0.f, 0.f, 0.f, 0.f};
    float lpart = 0.f;

    const int nkb = (qt >> 2) + 1;

    // barrier-free per-wave K-loop: wave handles jt = wave, wave+4, ...
    for (int jt = wave; jt < nkb; jt += 4) {
        const unsigned short* krow = kb + (size_t)jt * 64 * 64;
        float4v sv[4];
#pragma unroll
        for (int kt = 0; kt < 4; kt++) {
            const short8 ka = *(const short8*)(krow + (size_t)(kt * 16 + l16) * 64 + quad * 8);
            const short8 kc = *(const short8*)(krow + (size_t)(kt * 16 + l16) * 64 + 32 + quad * 8);
            float4v z = (float4v){0.f, 0.f, 0.f, 0.f};
            z = __builtin_amdgcn_mfma_f32_16x16x32_bf16(ka, qf0, z, 0, 0, 0);
            sv[kt] = __builtin_amdgcn_mfma_f32_16x16x32_bf16(kc, qf1, z, 0, 0, 0);
        }
        if (jt == nkb - 1) {
#pragma unroll
            for (int kt = 0; kt < 4; kt++)
#pragma unroll
                for (int r = 0; r < 4; r++)
                    if (jt * 64 + kt * 16 + quad * 4 + r > qrow) sv[kt][r] = -1e30f;
        }
#pragma unroll
        for (int kt = 0; kt < 4; kt++) {
            float p0 = exp2f(sv[kt][0] * LOG2E);
            float p1 = exp2f(sv[kt][1] * LOG2E);
            float p2 = exp2f(sv[kt][2] * LOG2E);
            float p3 = exp2f(sv[kt][3] * LOG2E);
            lpart += (p0 + p1) + (p2 + p3);
            unsigned int lo = (unsigned int)f2bf(p0) | ((unsigned int)f2bf(p1) << 16);
            unsigned int hi = (unsigned int)f2bf(p2) | ((unsigned int)f2bf(p3) << 16);
            unsigned long long w = ((unsigned long long)hi << 32) | lo;
            *(unsigned long long*)&P[wave][l16 * 72 + kt * 16 + quad * 4] = w;
        }
#pragma unroll
        for (int kc = 0; kc < 2; kc++) {
            const short8 pf = *(const short8*)&P[wave][l16 * 72 + kc * 32 + quad * 8];
#pragma unroll
            for (int ot = 0; ot < 4; ot++) {
                const short8 vf = *(const short8*)(vb + (size_t)(ot * 16 + l16) * 2048
                                                  + jt * 64 + kc * 32 + quad * 8);
                o[ot] = __builtin_amdgcn_mfma_f32_16x16x32_bf16(pf, vf, o[ot], 0, 0, 0);
            }
        }
    }

    lpart += __shfl_xor(lpart, 16);
    lpart += __shfl_xor(lpart, 32);
    __syncthreads();
#pragma unroll
    for (int r = 0; r < 4; r++)
#pragma unroll
        for (int ot = 0; ot < 4; ot++)
            Of[wave][quad * 4 + r][ot * 16 + l16] = o[ot][r];
    if (lane < 16) Ll[wave][lane] = lpart;
    __syncthreads();

    {
        const int row = tid >> 4;
        const int c0  = (tid & 15) * 4;
        const float lsum = Ll[0][row] + Ll[1][row] + Ll[2][row] + Ll[3][row];
        float4v v0 = *(const float4v*)&Of[0][row][c0];
        float4v v1 = *(const float4v*)&Of[1][row][c0];
        float4v v2 = *(const float4v*)&Of[2][row][c0];
        float4v v3 = *(const float4v*)&Of[3][row][c0];
        float4v res;
        const float inv = 1.0f / lsum;
#pragma unroll
        for (int j = 0; j < 4; j++)
            res[j] = ((v0[j] + v1[j]) + (v2[j] + v3[j])) * inv;
        float* ob = out + (size_t)b * 131072 + (size_t)(t0 + row) * 64 + c0;
        *(float4v*)ob = res;
    }
}

// ---------------------------------------------------------------------------
extern "C" void kernel_launch(void* const* d_in, const int* in_sizes, int n_in,
                              void* d_out, int out_size, void* d_ws, size_t ws_size,
                              hipStream_t stream) {
    const float* x  = (const float*)d_in[0];
    const float* Wk = (const float*)d_in[1];
    const float* Wq = (const float*)d_in[2];
    const float* Wv = (const float*)d_in[3];
    float* out = (float*)d_out;

    // Workspace: Wb 384 KB (+pad) | qs 2 MB | ks 2 MB | vT 2 MB
    unsigned short* Wb  = (unsigned short*)d_ws;
    unsigned short* qsb = (unsigned short*)((char*)d_ws + 393216);
    unsigned short* ksb = qsb + 1048576;
    unsigned short* vTb = ksb + 1048576;

    hipLaunchKernelGGL(wconv_kernel, dim3(768), dim3(256), 0, stream, Wk, Wq, Wv, Wb);
    hipLaunchKernelGGL(proj_kernel, dim3(512), dim3(256), 0, stream, x, Wb, qsb, ksb, vTb);
    hipLaunchKernelGGL(attn_kernel, dim3(1024), dim3(256), 0, stream, qsb, ksb, vTb, out);
}

// Round 7
// 154.558 us; speedup vs baseline: 1.0892x; 1.0892x over previous
//
#include <hip/hip_runtime.h>
#include <hip/hip_bf16.h>

typedef __attribute__((ext_vector_type(8))) short short8;
typedef __attribute__((ext_vector_type(4))) float float4v;

#define LOG2E 1.44269504088896340736f

__device__ __forceinline__ unsigned short f2bf(float f) {
    unsigned int u = __float_as_uint(f);
    unsigned int r = (u + 0x7fffu + ((u >> 16) & 1u)) >> 16;  // RNE
    return (unsigned short)r;
}

// ---------------------------------------------------------------------------
// Kernel 1: projection GEMM — round-18: WCONV FUSED INTO STAGING.
// Decomposition from R17 (attn surfaced at 51.4): total = ~77us fixed
// (fillBuffer + launch gaps + wconv) + proj(40) + attn(33). The only
// controllable piece of the 77 is the wconv dispatch. This round: drop the
// wconv kernel; proj stages B directly from Wk/Wq/Wv fp32 with fused
// f2bf conversion (reg-staged: 2x dwordx4 -> 8x f2bf -> ds_write_b128).
// Geometry/sync = R13 (best measured, ~40us): 256 thr, 4 waves, M=32,
// grid 512, dbuf LDS 48KB, 1 barrier/iter, counted vmcnt.
// vmcnt ledger (issue order per iter: [12 B][4 A], pinned by asm clobbers):
//   steady queue at wait = A(kt+1)[4] B(kt+1)[12] A(kt+2)[4];
//   vmcnt(4) drains A(kt+1) (used next iter) + B(kt+1) (about to ds_write),
//   leaves A(kt+2) flying. kt==14 -> vmcnt(0) (no A(16) behind B(15)).
// Prologue: issue B(0)[12], A(0)[4], A(1)[4]; vmcnt(4) leaves A(1) flying.
// XOR swizzle on the WRITE side (source linear -> coalesced 128B rows;
// LDS chunk = (l&7)^(l>>3)); read side identical to R13/R16 (verified).
// WAR: write to buf (kt+1)&1 happens after the barrier that ends iter
// kt-1's reads of that buffer. RAW: lgkmcnt(0)+barrier before reads.
// W-row base pointers (Wk/Wq/Wv select) hoisted out of the K-loop.
// ---------------------------------------------------------------------------
__global__ __launch_bounds__(256) void proj_kernel(
    const float* __restrict__ x, const float* __restrict__ Wk,
    const float* __restrict__ Wq, const float* __restrict__ Wv,
    unsigned short* __restrict__ qs, unsigned short* __restrict__ ks,
    unsigned short* __restrict__ vT) {
    __shared__ unsigned short Bl[2][12288];  // 2 x 192 rows x 64 ushort, 48 KB

    const int tid  = threadIdx.x;
    const int lane = tid & 63;
    const int wave = tid >> 6;
    const int rg   = wave & 1;   // row group
    const int g    = wave >> 1;  // n-tile group
    const int quad = lane >> 4;
    const int l16  = lane & 15;
    const int t0   = blockIdx.x * 32;

    // staging geometry: wave covers regions wave*6..+5; region = 8 rows of
    // 128 B(bf16); lane l -> (row l>>3, source chunk l&7 = 8 floats = 32 B),
    // LDS dest chunk (l&7)^(l>>3) (XOR swizzle on write side).
    const int srow_in = lane >> 3;                 // 0..7
    const int schunk  = lane & 7;                  // linear source chunk
    const int wchunk  = schunk ^ srow_in;          // swizzled LDS chunk

    // fused wconv: per-region fp32 W row base (combined row id 0..191)
    const float* wrow[6];
#pragma unroll
    for (int i = 0; i < 6; i++) {
        const int rowg = (wave * 6 + i) * 8 + srow_in;
        wrow[i] = (rowg < 64)  ? (Wk + (size_t)rowg * 1024)
                : (rowg < 128) ? (Wq + (size_t)(rowg - 64) * 1024)
                               : (Wv + (size_t)(rowg - 128) * 1024);
    }

    const int rowA = t0 + rg * 16 + l16;
    const float* xr = x + (size_t)rowA * 1024;

    float4v acc[6];
#pragma unroll
    for (int n = 0; n < 6; n++) acc[n] = (float4v){0.f, 0.f, 0.f, 0.f};

#define STAGE_LOAD(REG, KN)                                                   \
    {                                                                         \
        _Pragma("unroll")                                                     \
        for (int i = 0; i < 6; i++) {                                         \
            const float* src = wrow[i] + (KN) + schunk * 8;                   \
            REG[i * 2]     = *(const float4v*)(src);                          \
            REG[i * 2 + 1] = *(const float4v*)(src + 4);                      \
        }                                                                     \
    }

#define STAGE_WRITE(BUF, REG)                                                 \
    {                                                                         \
        _Pragma("unroll")                                                     \
        for (int i = 0; i < 6; i++) {                                         \
            short8 w;                                                         \
            _Pragma("unroll")                                                 \
            for (int j = 0; j < 4; j++) {                                     \
                w[j]     = (short)f2bf(REG[i * 2][j]);                        \
                w[4 + j] = (short)f2bf(REG[i * 2 + 1][j]);                    \
            }                                                                 \
            *(short8*)&Bl[BUF][(wave * 6 + i) * 512 + srow_in * 64 + wchunk * 8] = w; \
        }                                                                     \
    }

#define LOAD_A(DST, KN)                                             \
    {                                                               \
        DST[0] = *(const float4v*)(xr + (KN) + quad * 8);           \
        DST[1] = *(const float4v*)(xr + (KN) + quad * 8 + 4);       \
        DST[2] = *(const float4v*)(xr + (KN) + 32 + quad * 8);      \
        DST[3] = *(const float4v*)(xr + (KN) + 32 + quad * 8 + 4);  \
    }

    // prologue: B(0)[12], A(0)[4], A(1)[4]; vmcnt(4) -> B(0)+A(0) landed,
    // A(1) keeps flying; convert+write buf0; barrier.
    float4v breg[12];
    float4v a0[4], a1[4];
    STAGE_LOAD(breg, 0)
    asm volatile("" ::: "memory");  // pin: B-loads before A-loads
    LOAD_A(a0, 0)
    LOAD_A(a1, 64)
    asm volatile("s_waitcnt vmcnt(4)" ::: "memory");
    STAGE_WRITE(0, breg)
    asm volatile("s_waitcnt lgkmcnt(0)" ::: "memory");
    __builtin_amdgcn_s_barrier();

    const int swz = l16 & 7;

#pragma unroll
    for (int kt = 0; kt < 16; kt++) {
        // issue next B tile's global loads FIRST (oldest in vm queue)
        if (kt < 15) STAGE_LOAD(breg, (kt + 1) * 64)
        asm volatile("" ::: "memory");  // pin: B-loads before A-loads
        float4v an[4];
        if (kt < 14) LOAD_A(an, (kt + 2) * 64)
        asm volatile("" ::: "memory");  // pin: vm issue group closed

        // compute tile kt from LDS buf (kt&1) using a0 = A(kt)
        const unsigned short* Bc = Bl[kt & 1];
#pragma unroll
        for (int kc = 0; kc < 2; kc++) {
            short8 af;
#pragma unroll
            for (int j = 0; j < 4; j++) af[j] = (short)f2bf(a0[kc * 2][j]);
#pragma unroll
            for (int j = 0; j < 4; j++) af[4 + j] = (short)f2bf(a0[kc * 2 + 1][j]);
#pragma unroll
            for (int n = 0; n < 6; n++) {
                const int row  = (g * 6 + n) * 16 + l16;
                const int coff = ((kc * 4 + quad) ^ swz) * 8;
                const short8 bf = *(const short8*)&Bc[row * 64 + coff];
                acc[n] = __builtin_amdgcn_mfma_f32_16x16x32_bf16(af, bf, acc[n], 0, 0, 0);
            }
        }

        if (kt < 15) {
            // drain B(kt+1) (+A(kt+1)); keep A(kt+2) flying. Tail kt==14:
            // no A(16) behind B(15) -> vmcnt(0).
            if (kt < 14) {
                asm volatile("s_waitcnt vmcnt(4)" ::: "memory");
            } else {
                asm volatile("s_waitcnt vmcnt(0)" ::: "memory");
            }
            STAGE_WRITE((kt + 1) & 1, breg)
            asm volatile("s_waitcnt lgkmcnt(0)" ::: "memory");
            __builtin_amdgcn_s_barrier();
        }

        if (kt < 14) {
#pragma unroll
            for (int i = 0; i < 4; i++) { a0[i] = a1[i]; a1[i] = an[i]; }
        } else if (kt < 15) {
#pragma unroll
            for (int i = 0; i < 4; i++) a0[i] = a1[i];
        }
    }
#undef STAGE_LOAD
#undef STAGE_WRITE
#undef LOAD_A

    // Epilogue. C layout: row = quad*4 + r, col = l16.
    const int rowD = t0 + rg * 16 + quad * 4;
#pragma unroll
    for (int r = 0; r < 4; r++) {
        const int t = rowD + r;
        const int b = t >> 11, tt = t & 2047;
        if (g == 0) {
#pragma unroll
            for (int n = 0; n < 4; n++)
                ks[(size_t)t * 64 + n * 16 + l16] = f2bf(acc[n][r]);
#pragma unroll
            for (int n = 4; n < 6; n++)
                qs[(size_t)t * 64 + (n - 4) * 16 + l16] = f2bf(acc[n][r] * 0.125f);
        } else {
#pragma unroll
            for (int n = 0; n < 2; n++)
                qs[(size_t)t * 64 + (n + 2) * 16 + l16] = f2bf(acc[n][r] * 0.125f);
#pragma unroll
            for (int n = 2; n < 6; n++)
                vT[(size_t)b * 131072 + (size_t)((n - 2) * 16 + l16) * 2048 + tt] = f2bf(acc[n][r]);
        }
    }
}

// ---------------------------------------------------------------------------
// Kernel 2: causal attention v3 — REVERTED to R11 verbatim (best measured:
// ~33us by decomposition). R17's de-staged variant regressed to 51us:
// direct per-fragment K/V reads were scattered 16B segments on the MFMA
// dependency chain with no compiler pipelining (VGPR collapsed to 48).
// ---------------------------------------------------------------------------
__global__ __launch_bounds__(256) void attn_kernel(
    const unsigned short* __restrict__ qs, const unsigned short* __restrict__ ks,
    const unsigned short* __restrict__ vT, float* __restrict__ out) {
    __shared__ unsigned short Kl[4 * 64 * 72];
    __shared__ unsigned short Vl[64 * 264];
    __shared__ unsigned short P[4][16 * 72];
    __shared__ float Ll[4][16];
    float* Of = (float*)Kl;  // merge buffer aliases Kl: [4][16][68] fp32

    const int tid  = threadIdx.x;
    const int lane = tid & 63;
    const int wave = tid >> 6;
    const int quad = lane >> 4;
    const int l16  = lane & 15;
    const int bx   = blockIdx.x;
    const int b    = bx & 7;
    const int i    = bx >> 3;
    const int qt   = (i & 1) ? (127 - (i >> 1)) : (i >> 1);
    const int t0   = qt * 16;

    const unsigned short* qb = qs + (size_t)b * 131072;
    const unsigned short* kb = ks + (size_t)b * 131072;
    const unsigned short* vb = vT + (size_t)b * 131072;

    const int ksr = tid >> 3;
    const int ksc = (tid & 7) * 8;
    const int vsr = tid >> 5;
    const int vsc = (tid & 31) * 8;

    const int qrow = t0 + l16;
    const short8 qf0 = *(const short8*)(qb + (size_t)qrow * 64 + quad * 8);
    const short8 qf1 = *(const short8*)(qb + (size_t)qrow * 64 + 32 + quad * 8);

    float4v o[4];
#pragma unroll
    for (int ot = 0; ot < 4; ot++) o[ot] = (float4v){0.f, 0.f, 0.f, 0.f};
    float lpart = 0.f;

    const int nkb  = (qt >> 2) + 1;
    const int nsup = (nkb + 3) >> 2;

    for (int s = 0; s < nsup; s++) {
        const int key0 = s * 256;
        __syncthreads();
#pragma unroll
        for (int i2 = 0; i2 < 8; i2++) {
            int kr = key0 + i2 * 32 + ksr; kr = kr < 2047 ? kr : 2047;
            *(short8*)&Kl[(i2 * 32 + ksr) * 72 + ksc] = *(const short8*)(kb + (size_t)kr * 64 + ksc);
        }
#pragma unroll
        for (int i2 = 0; i2 < 8; i2++) {
            const int orow = i2 * 8 + vsr;
            int kc2 = key0 + vsc; kc2 = kc2 < 2040 ? kc2 : 2040;
            *(short8*)&Vl[orow * 264 + vsc] = *(const short8*)(vb + (size_t)orow * 2048 + kc2);
        }
        __syncthreads();

        const int jt = s * 4 + wave;
        if (jt < nkb) {
            const int kbase = wave * 64;
            float4v sv[4];
#pragma unroll
            for (int kt = 0; kt < 4; kt++) {
                const short8 ka = *(const short8*)&Kl[(kbase + kt * 16 + l16) * 72 + quad * 8];
                const short8 kc = *(const short8*)&Kl[(kbase + kt * 16 + l16) * 72 + 32 + quad * 8];
                float4v z = (float4v){0.f, 0.f, 0.f, 0.f};
                z = __builtin_amdgcn_mfma_f32_16x16x32_bf16(ka, qf0, z, 0, 0, 0);
                sv[kt] = __builtin_amdgcn_mfma_f32_16x16x32_bf16(kc, qf1, z, 0, 0, 0);
            }
            if (jt == nkb - 1) {
#pragma unroll
                for (int kt = 0; kt < 4; kt++)
#pragma unroll
                    for (int r = 0; r < 4; r++)
                        if (jt * 64 + kt * 16 + quad * 4 + r > qrow) sv[kt][r] = -1e30f;
            }
#pragma unroll
            for (int kt = 0; kt < 4; kt++) {
                float p0 = exp2f(sv[kt][0] * LOG2E);
                float p1 = exp2f(sv[kt][1] * LOG2E);
                float p2 = exp2f(sv[kt][2] * LOG2E);
                float p3 = exp2f(sv[kt][3] * LOG2E);
                lpart += (p0 + p1) + (p2 + p3);
                unsigned int lo = (unsigned int)f2bf(p0) | ((unsigned int)f2bf(p1) << 16);
                unsigned int hi = (unsigned int)f2bf(p2) | ((unsigned int)f2bf(p3) << 16);
                unsigned long long w = ((unsigned long long)hi << 32) | lo;
                *(unsigned long long*)&P[wave][l16 * 72 + kt * 16 + quad * 4] = w;
            }
#pragma unroll
            for (int kc = 0; kc < 2; kc++) {
                const short8 pf = *(const short8*)&P[wave][l16 * 72 + kc * 32 + quad * 8];
#pragma unroll
                for (int ot = 0; ot < 4; ot++) {
                    const short8 vf = *(const short8*)&Vl[(ot * 16 + l16) * 264 + wave * 64 + kc * 32 + quad * 8];
                    o[ot] = __builtin_amdgcn_mfma_f32_16x16x32_bf16(pf, vf, o[ot], 0, 0, 0);
                }
            }
        }
    }

    lpart += __shfl_xor(lpart, 16);
    lpart += __shfl_xor(lpart, 32);
    __syncthreads();
#pragma unroll
    for (int r = 0; r < 4; r++)
#pragma unroll
        for (int ot = 0; ot < 4; ot++)
            Of[wave * 1088 + (quad * 4 + r) * 68 + ot * 16 + l16] = o[ot][r];
    if (lane < 16) Ll[wave][lane] = lpart;
    __syncthreads();

    {
        const int row = tid >> 4;
        const int c0  = (tid & 15) * 4;
        const float lsum = Ll[0][row] + Ll[1][row] + Ll[2][row] + Ll[3][row];
        float4v v0 = *(const float4v*)&Of[0 * 1088 + row * 68 + c0];
        float4v v1 = *(const float4v*)&Of[1 * 1088 + row * 68 + c0];
        float4v v2 = *(const float4v*)&Of[2 * 1088 + row * 68 + c0];
        float4v v3 = *(const float4v*)&Of[3 * 1088 + row * 68 + c0];
        float4v res;
        const float inv = 1.0f / lsum;
#pragma unroll
        for (int j = 0; j < 4; j++)
            res[j] = ((v0[j] + v1[j]) + (v2[j] + v3[j])) * inv;
        float* ob = out + (size_t)b * 131072 + (size_t)(t0 + row) * 64 + c0;
        *(float4v*)ob = res;
    }
}

// ---------------------------------------------------------------------------
extern "C" void kernel_launch(void* const* d_in, const int* in_sizes, int n_in,
                              void* d_out, int out_size, void* d_ws, size_t ws_size,
                              hipStream_t stream) {
    const float* x  = (const float*)d_in[0];
    const float* Wk = (const float*)d_in[1];
    const float* Wq = (const float*)d_in[2];
    const float* Wv = (const float*)d_in[3];
    float* out = (float*)d_out;

    // Workspace: (384 KB reserved, unused) | qs 2 MB | ks 2 MB | vT 2 MB
    unsigned short* qsb = (unsigned short*)((char*)d_ws + 393216);
    unsigned short* ksb = qsb + 1048576;
    unsigned short* vTb = ksb + 1048576;

    hipLaunchKernelGGL(proj_kernel, dim3(512), dim3(256), 0, stream, x, Wk, Wq, Wv, qsb, ksb, vTb);
    hipLaunchKernelGGL(attn_kernel, dim3(1024), dim3(256), 0, stream, qsb, ksb, vTb, out);
}

// Round 8
// 154.227 us; speedup vs baseline: 1.0915x; 1.0022x over previous
//
#include <hip/hip_runtime.h>
#include <hip/hip_bf16.h>

typedef __attribute__((ext_vector_type(8))) short short8;
typedef __attribute__((ext_vector_type(4))) float float4v;

#define LOG2E 1.44269504088896340736f

typedef __attribute__((address_space(1))) const unsigned int gu32;
typedef __attribute__((address_space(3))) unsigned int su32;

__device__ __forceinline__ unsigned short f2bf(float f) {
    unsigned int u = __float_as_uint(f);
    unsigned int r = (u + 0x7fffu + ((u >> 16) & 1u)) >> 16;  // RNE
    return (unsigned short)r;
}

// ---------------------------------------------------------------------------
// Kernel 1: convert Wk|Wq|Wv (fp32) -> combined bf16 Wb[192][1024]
// (restored: R18's fused variant cost proj +8.5us for -4us dispatch)
// ---------------------------------------------------------------------------
__global__ void wconv_kernel(const float* __restrict__ Wk, const float* __restrict__ Wq,
                             const float* __restrict__ Wv, unsigned short* __restrict__ Wb) {
    int i = blockIdx.x * 256 + threadIdx.x;
    if (i >= 192 * 1024) return;
    float v;
    if (i < 65536)       v = Wk[i];
    else if (i < 131072) v = Wq[i - 65536];
    else                 v = Wv[i - 131072];
    Wb[i] = f2bf(v);
}

// ---------------------------------------------------------------------------
// Kernel 2: projection GEMM — round-19: R13 + PIPELINE DEPTH 2 (3 buffers).
// Quantitative invariance: R13 (4 waves) and R15 (8 waves, half per-wave
// work) have identical total barrier-iters and identical duration ->
// T_iter ~ 6000 device-cy is a latency constant, insensitive to work and
// TLP. The only never-tested variable: pipeline DEPTH (stage cover was 1
// iter in every variant). This round: 3-buffer LDS rotation (72 KB, still
// 2 blocks/CU at 144 KB) -> 2 full iterations of cover for stage AND A.
// vmcnt ledger (issue order per iter: [6 stage][4 A], pinned):
//   steady queue at iter-kt top = S(kt)[6] A(kt)[4] S(kt+1)[6] A(kt+1)[4];
//   vmcnt(10) drains S(kt)+A(kt), leaves the kt+1 set flying (2-iter cover
//   for the kt+2 set issued below). kt=15 -> vmcnt(0).
// WAR: S(kt+2) writes buf (kt+2)%3 == (kt-1)%3, read at iter kt-1; those
// reads end before this iter's barrier. RAW: vmcnt+barrier before reads.
// Everything else bit-identical to R13 (geometry, swizzle, epilogue).
// ---------------------------------------------------------------------------
__global__ __launch_bounds__(256) void proj_kernel(
    const float* __restrict__ x, const unsigned short* __restrict__ Wb,
    unsigned short* __restrict__ qs, unsigned short* __restrict__ ks,
    unsigned short* __restrict__ vT) {
    __shared__ unsigned short Bl[3][12288];  // 3 x 192 rows x 64 ushort, 72 KB

    const int tid  = threadIdx.x;
    const int lane = tid & 63;
    const int wave = tid >> 6;
    const int rg   = wave & 1;   // row group
    const int g    = wave >> 1;  // n-tile group
    const int quad = lane >> 4;
    const int l16  = lane & 15;
    const int t0   = blockIdx.x * 32;

    // async staging geometry: wave covers regions wave*6..+5; region = 8 rows
    // of 128 B; lane l -> (row l>>3, LDS chunk l&7), source chunk (l&7)^(l>>3)
    const int srow_in = lane >> 3;                 // 0..7
    const int csrc    = (lane & 7) ^ srow_in;      // XOR swizzle source chunk

    const int rowA = t0 + rg * 16 + l16;
    const float* xr = x + (size_t)rowA * 1024;

    float4v acc[6];
#pragma unroll
    for (int n = 0; n < 6; n++) acc[n] = (float4v){0.f, 0.f, 0.f, 0.f};

#define STAGE_B(BUF, KN)                                                          \
    {                                                                             \
        _Pragma("unroll")                                                         \
        for (int i = 0; i < 6; i++) {                                             \
            const int region = wave * 6 + i;                                      \
            const int rowg   = region * 8 + srow_in;                              \
            const unsigned short* src = Wb + (size_t)rowg * 1024 + (KN) + csrc * 8; \
            __builtin_amdgcn_global_load_lds((gu32*)src,                          \
                                             (su32*)&Bl[BUF][region * 512],       \
                                             16, 0, 0);                           \
        }                                                                         \
    }

#define LOAD_A(DST, KN)                                             \
    {                                                               \
        DST[0] = *(const float4v*)(xr + (KN) + quad * 8);           \
        DST[1] = *(const float4v*)(xr + (KN) + quad * 8 + 4);       \
        DST[2] = *(const float4v*)(xr + (KN) + 32 + quad * 8);      \
        DST[3] = *(const float4v*)(xr + (KN) + 32 + quad * 8 + 4);  \
    }

    // prologue — queue oldest-first: S(0)[6] A(0)[4] S(1)[6] A(1)[4]
    STAGE_B(0, 0)
    asm volatile("" ::: "memory");
    float4v a0[4], a1[4];
    LOAD_A(a0, 0)
    asm volatile("" ::: "memory");
    STAGE_B(1, 64)
    asm volatile("" ::: "memory");
    LOAD_A(a1, 64)

    const int swz = l16 & 7;

#pragma unroll
    for (int kt = 0; kt < 16; kt++) {
        __builtin_amdgcn_sched_barrier(0);
        // drain S(kt)+A(kt); leave S(kt+1),A(kt+1) (10) flying.
        if (kt < 15) {
            asm volatile("s_waitcnt vmcnt(10)" ::: "memory");
        } else {
            asm volatile("s_waitcnt vmcnt(0)" ::: "memory");
        }
        __builtin_amdgcn_s_barrier();
        // issue the kt+2 set (2 iterations of cover)
        if (kt < 14) {
            STAGE_B((kt + 2) % 3, (kt + 2) * 64)
            asm volatile("" ::: "memory");  // pin: stages before A-loads
        }
        float4v an[4];
        if (kt < 14) {
            LOAD_A(an, (kt + 2) * 64)
            asm volatile("" ::: "memory");  // close vm issue group
        }
        const unsigned short* Bc = Bl[kt % 3];
#pragma unroll
        for (int kc = 0; kc < 2; kc++) {
            short8 af;
#pragma unroll
            for (int j = 0; j < 4; j++) af[j] = (short)f2bf(a0[kc * 2][j]);
#pragma unroll
            for (int j = 0; j < 4; j++) af[4 + j] = (short)f2bf(a0[kc * 2 + 1][j]);
#pragma unroll
            for (int n = 0; n < 6; n++) {
                const int row  = (g * 6 + n) * 16 + l16;
                const int coff = ((kc * 4 + quad) ^ swz) * 8;
                const short8 bf = *(const short8*)&Bc[row * 64 + coff];
                acc[n] = __builtin_amdgcn_mfma_f32_16x16x32_bf16(af, bf, acc[n], 0, 0, 0);
            }
        }
        if (kt < 14) {
#pragma unroll
            for (int i = 0; i < 4; i++) { a0[i] = a1[i]; a1[i] = an[i]; }
        } else if (kt < 15) {
#pragma unroll
            for (int i = 0; i < 4; i++) a0[i] = a1[i];
        }
    }
#undef STAGE_B
#undef LOAD_A

    // Epilogue. C layout: row = quad*4 + r, col = l16.
    const int rowD = t0 + rg * 16 + quad * 4;
#pragma unroll
    for (int r = 0; r < 4; r++) {
        const int t = rowD + r;
        const int b = t >> 11, tt = t & 2047;
        if (g == 0) {
#pragma unroll
            for (int n = 0; n < 4; n++)
                ks[(size_t)t * 64 + n * 16 + l16] = f2bf(acc[n][r]);
#pragma unroll
            for (int n = 4; n < 6; n++)
                qs[(size_t)t * 64 + (n - 4) * 16 + l16] = f2bf(acc[n][r] * 0.125f);
        } else {
#pragma unroll
            for (int n = 0; n < 2; n++)
                qs[(size_t)t * 64 + (n + 2) * 16 + l16] = f2bf(acc[n][r] * 0.125f);
#pragma unroll
            for (int n = 2; n < 6; n++)
                vT[(size_t)b * 131072 + (size_t)((n - 2) * 16 + l16) * 2048 + tt] = f2bf(acc[n][r]);
        }
    }
}

// ---------------------------------------------------------------------------
// Kernel 3: causal attention v3 — R11 verbatim (best measured: ~33us)
// ---------------------------------------------------------------------------
__global__ __launch_bounds__(256) void attn_kernel(
    const unsigned short* __restrict__ qs, const unsigned short* __restrict__ ks,
    const unsigned short* __restrict__ vT, float* __restrict__ out) {
    __shared__ unsigned short Kl[4 * 64 * 72];
    __shared__ unsigned short Vl[64 * 264];
    __shared__ unsigned short P[4][16 * 72];
    __shared__ float Ll[4][16];
    float* Of = (float*)Kl;  // merge buffer aliases Kl: [4][16][68] fp32

    const int tid  = threadIdx.x;
    const int lane = tid & 63;
    const int wave = tid >> 6;
    const int quad = lane >> 4;
    const int l16  = lane & 15;
    const int bx   = blockIdx.x;
    const int b    = bx & 7;
    const int i    = bx >> 3;
    const int qt   = (i & 1) ? (127 - (i >> 1)) : (i >> 1);
    const int t0   = qt * 16;

    const unsigned short* qb = qs + (size_t)b * 131072;
    const unsigned short* kb = ks + (size_t)b * 131072;
    const unsigned short* vb = vT + (size_t)b * 131072;

    const int ksr = tid >> 3;
    const int ksc = (tid & 7) * 8;
    const int vsr = tid >> 5;
    const int vsc = (tid & 31) * 8;

    const int qrow = t0 + l16;
    const short8 qf0 = *(const short8*)(qb + (size_t)qrow * 64 + quad * 8);
    const short8 qf1 = *(const short8*)(qb + (size_t)qrow * 64 + 32 + quad * 8);

    float4v o[4];
#pragma unroll
    for (int ot = 0; ot < 4; ot++) o[ot] = (float4v){0.f, 0.f, 0.f, 0.f};
    float lpart = 0.f;

    const int nkb  = (qt >> 2) + 1;
    const int nsup = (nkb + 3) >> 2;

    for (int s = 0; s < nsup; s++) {
        const int key0 = s * 256;
        __syncthreads();
#pragma unroll
        for (int i2 = 0; i2 < 8; i2++) {
            int kr = key0 + i2 * 32 + ksr; kr = kr < 2047 ? kr : 2047;
            *(short8*)&Kl[(i2 * 32 + ksr) * 72 + ksc] = *(const short8*)(kb + (size_t)kr * 64 + ksc);
        }
#pragma unroll
        for (int i2 = 0; i2 < 8; i2++) {
            const int orow = i2 * 8 + vsr;
            int kc2 = key0 + vsc; kc2 = kc2 < 2040 ? kc2 : 2040;
            *(short8*)&Vl[orow * 264 + vsc] = *(const short8*)(vb + (size_t)orow * 2048 + kc2);
        }
        __syncthreads();

        const int jt = s * 4 + wave;
        if (jt < nkb) {
            const int kbase = wave * 64;
            float4v sv[4];
#pragma unroll
            for (int kt = 0; kt < 4; kt++) {
                const short8 ka = *(const short8*)&Kl[(kbase + kt * 16 + l16) * 72 + quad * 8];
                const short8 kc = *(const short8*)&Kl[(kbase + kt * 16 + l16) * 72 + 32 + quad * 8];
                float4v z = (float4v){0.f, 0.f, 0.f, 0.f};
                z = __builtin_amdgcn_mfma_f32_16x16x32_bf16(ka, qf0, z, 0, 0, 0);
                sv[kt] = __builtin_amdgcn_mfma_f32_16x16x32_bf16(kc, qf1, z, 0, 0, 0);
            }
            if (jt == nkb - 1) {
#pragma unroll
                for (int kt = 0; kt < 4; kt++)
#pragma unroll
                    for (int r = 0; r < 4; r++)
                        if (jt * 64 + kt * 16 + quad * 4 + r > qrow) sv[kt][r] = -1e30f;
            }
#pragma unroll
            for (int kt = 0; kt < 4; kt++) {
                float p0 = exp2f(sv[kt][0] * LOG2E);
                float p1 = exp2f(sv[kt][1] * LOG2E);
                float p2 = exp2f(sv[kt][2] * LOG2E);
                float p3 = exp2f(sv[kt][3] * LOG2E);
                lpart += (p0 + p1) + (p2 + p3);
                unsigned int lo = (unsigned int)f2bf(p0) | ((unsigned int)f2bf(p1) << 16);
                unsigned int hi = (unsigned int)f2bf(p2) | ((unsigned int)f2bf(p3) << 16);
                unsigned long long w = ((unsigned long long)hi << 32) | lo;
                *(unsigned long long*)&P[wave][l16 * 72 + kt * 16 + quad * 4] = w;
            }
#pragma unroll
            for (int kc = 0; kc < 2; kc++) {
                const short8 pf = *(const short8*)&P[wave][l16 * 72 + kc * 32 + quad * 8];
#pragma unroll
                for (int ot = 0; ot < 4; ot++) {
                    const short8 vf = *(const short8*)&Vl[(ot * 16 + l16) * 264 + wave * 64 + kc * 32 + quad * 8];
                    o[ot] = __builtin_amdgcn_mfma_f32_16x16x32_bf16(pf, vf, o[ot], 0, 0, 0);
                }
            }
        }
    }

    lpart += __shfl_xor(lpart, 16);
    lpart += __shfl_xor(lpart, 32);
    __syncthreads();
#pragma unroll
    for (int r = 0; r < 4; r++)
#pragma unroll
        for (int ot = 0; ot < 4; ot++)
            Of[wave * 1088 + (quad * 4 + r) * 68 + ot * 16 + l16] = o[ot][r];
    if (lane < 16) Ll[wave][lane] = lpart;
    __syncthreads();

    {
        const int row = tid >> 4;
        const int c0  = (tid & 15) * 4;
        const float lsum = Ll[0][row] + Ll[1][row] + Ll[2][row] + Ll[3][row];
        float4v v0 = *(const float4v*)&Of[0 * 1088 + row * 68 + c0];
        float4v v1 = *(const float4v*)&Of[1 * 1088 + row * 68 + c0];
        float4v v2 = *(const float4v*)&Of[2 * 1088 + row * 68 + c0];
        float4v v3 = *(const float4v*)&Of[3 * 1088 + row * 68 + c0];
        float4v res;
        const float inv = 1.0f / lsum;
#pragma unroll
        for (int j = 0; j < 4; j++)
            res[j] = ((v0[j] + v1[j]) + (v2[j] + v3[j])) * inv;
        float* ob = out + (size_t)b * 131072 + (size_t)(t0 + row) * 64 + c0;
        *(float4v*)ob = res;
    }
}

// ---------------------------------------------------------------------------
extern "C" void kernel_launch(void* const* d_in, const int* in_sizes, int n_in,
                              void* d_out, int out_size, void* d_ws, size_t ws_size,
                              hipStream_t stream) {
    const float* x  = (const float*)d_in[0];
    const float* Wk = (const float*)d_in[1];
    const float* Wq = (const float*)d_in[2];
    const float* Wv = (const float*)d_in[3];
    float* out = (float*)d_out;

    // Workspace: Wb 384 KB (+pad) | qs 2 MB | ks 2 MB | vT 2 MB
    unsigned short* Wb  = (unsigned short*)d_ws;
    unsigned short* qsb = (unsigned short*)((char*)d_ws + 393216);
    unsigned short* ksb = qsb + 1048576;
    unsigned short* vTb = ksb + 1048576;

    hipLaunchKernelGGL(wconv_kernel, dim3(768), dim3(256), 0, stream, Wk, Wq, Wv, Wb);
    hipLaunchKernelGGL(proj_kernel, dim3(512), dim3(256), 0, stream, x, Wb, qsb, ksb, vTb);
    hipLaunchKernelGGL(attn_kernel, dim3(1024), dim3(256), 0, stream, qsb, ksb, vTb, out);
}

// Round 9
// 142.352 us; speedup vs baseline: 1.1826x; 1.0834x over previous
//
#include <hip/hip_runtime.h>
#include <hip/hip_bf16.h>

typedef __attribute__((ext_vector_type(8))) short short8;
typedef __attribute__((ext_vector_type(4))) float float4v;

#define LOG2E 1.44269504088896340736f

__device__ __forceinline__ unsigned short f2bf(float f) {
    unsigned int u = __float_as_uint(f);
    unsigned int r = (u + 0x7fffu + ((u >> 16) & 1u)) >> 16;  // RNE
    return (unsigned short)r;
}

// ---------------------------------------------------------------------------
// Kernel 1: convert Wk|Wq|Wv (fp32) -> combined bf16 Wb[192][1024]
// ---------------------------------------------------------------------------
__global__ void wconv_kernel(const float* __restrict__ Wk, const float* __restrict__ Wq,
                             const float* __restrict__ Wv, unsigned short* __restrict__ Wb) {
    int i = blockIdx.x * 256 + threadIdx.x;
    if (i >= 192 * 1024) return;
    float v;
    if (i < 65536)       v = Wk[i];
    else if (i < 131072) v = Wq[i - 65536];
    else                 v = Wv[i - 131072];
    Wb[i] = f2bf(v);
}

// ---------------------------------------------------------------------------
// Kernel 2: projection GEMM — round-20: COALESCED-A via LDS + no DMA.
// R19 (2-iter stage cover) was neutral -> exposed latency is NOT the cost.
// Line-request accounting finally orders all variants consistently:
// R13 ~1790 req/CU/iter = 40us; R14/R15/R16 ~2820 = 47-50us. The A-loads
// are the pathology: xr depends on l16 -> consecutive lanes 4KB apart,
// ~32 lines per wave64 load + full g-duplication (A = 1024 of R13's 1790).
// Fix: block-cooperative COALESCED A staging through LDS (thread t -> row
// t>>3, 32B contiguous; requests 1024 -> 256/block-iter), f2bf moved to
// stage time (inner-loop conversion eliminated), fragments read back via
// the same verified XOR-swizzle b128 pattern as B. B switches to R16's
// reg-staged writes (no LDS-DMA -> second suspect removed; R16 measured
// 0 bank conflicts for this exact write pattern). Counted-vmcnt ledger:
//   per iter issue [6 B(kt+1)][2 A(kt+2)]; queue at end =
//   A(kt+1)2 B(kt+1)6 A(kt+2)2 -> vmcnt(2) drains the two sets needed by
//   the ds_writes, leaves A(kt+2) flying. kt==14 -> vmcnt(0) (no A(16)).
//   Single barrier per iter after lgkmcnt(0).
// WAR: writes target buf (kt+1)&1, last read in iter kt-1 before its
// barrier. aS sets statically indexed under full unroll (rule #20).
// ---------------------------------------------------------------------------
__global__ __launch_bounds__(256) void proj_kernel(
    const float* __restrict__ x, const unsigned short* __restrict__ Wb,
    unsigned short* __restrict__ qs, unsigned short* __restrict__ ks,
    unsigned short* __restrict__ vT) {
    __shared__ unsigned short Bl[2][12288];  // 2 x 192 rows x 64 ushort, 48 KB
    __shared__ unsigned short Al[2][2048];   // 2 x 32 rows x 64 ushort, 8 KB

    const int tid  = threadIdx.x;
    const int lane = tid & 63;
    const int wave = tid >> 6;
    const int rg   = wave & 1;   // row group (A read)
    const int g    = wave >> 1;  // n-tile group
    const int quad = lane >> 4;
    const int l16  = lane & 15;
    const int t0   = blockIdx.x * 32;

    // B staging: wave covers regions wave*6..+5; region = 8 rows of 128 B;
    // lane l -> (row l>>3, source chunk l&7 [contiguous 128B per 8 lanes]),
    // LDS chunk (l&7)^(l>>3).
    const int brow_in = lane >> 3;
    const int bchunk  = lane & 7;
    const int bwchunk = bchunk ^ brow_in;

    // A staging (block-cooperative, coalesced): thread t -> row t>>3 (0..31),
    // colgroup t&7 (8 floats = 32 B contiguous). LDS chunk (t&7)^(row&7).
    const int ar = tid >> 3;
    const int ak = tid & 7;
    const float* xsrc = x + (size_t)(t0 + ar) * 1024 + ak * 8;
    const int awoff = ar * 64 + ((ak ^ (ar & 7)) * 8);

    const int arow = rg * 16 + l16;   // A fragment read row
    const int swz  = l16 & 7;

    float4v acc[6];
#pragma unroll
    for (int n = 0; n < 6; n++) acc[n] = (float4v){0.f, 0.f, 0.f, 0.f};

#define STAGE_LOAD_B(REG, KN)                                                     \
    {                                                                             \
        _Pragma("unroll")                                                         \
        for (int i = 0; i < 6; i++) {                                             \
            const int rowg = (wave * 6 + i) * 8 + brow_in;                        \
            REG[i] = *(const short8*)(Wb + (size_t)rowg * 1024 + (KN) + bchunk * 8); \
        }                                                                         \
    }

#define STAGE_WRITE_B(BUF, REG)                                                   \
    {                                                                             \
        _Pragma("unroll")                                                         \
        for (int i = 0; i < 6; i++)                                               \
            *(short8*)&Bl[BUF][(wave * 6 + i) * 512 + brow_in * 64 + bwchunk * 8] = REG[i]; \
    }

#define LOAD_A_G(F0, F1, KN)                              \
    {                                                     \
        F0 = *(const float4v*)(xsrc + (KN));              \
        F1 = *(const float4v*)(xsrc + (KN) + 4);          \
    }

#define STAGE_WRITE_A(BUF, F0, F1)                        \
    {                                                     \
        short8 w;                                         \
        _Pragma("unroll")                                 \
        for (int j = 0; j < 4; j++) {                     \
            w[j]     = (short)f2bf(F0[j]);                \
            w[4 + j] = (short)f2bf(F1[j]);                \
        }                                                 \
        *(short8*)&Al[BUF][awoff] = w;                    \
    }

    // prologue — issue order: B(0)[6], A(0)[2], A(1)[2]; vmcnt(2) drains
    // B(0)+A(0), leaves A(1) flying; write buf0; barrier.
    short8 breg[6];
    float4v aS[2][2];
    float4v a0f0, a0f1;
    STAGE_LOAD_B(breg, 0)
    asm volatile("" ::: "memory");
    LOAD_A_G(a0f0, a0f1, 0)
    asm volatile("" ::: "memory");
    LOAD_A_G(aS[1][0], aS[1][1], 64)
    asm volatile("s_waitcnt vmcnt(2)" ::: "memory");
    STAGE_WRITE_B(0, breg)
    STAGE_WRITE_A(0, a0f0, a0f1)
    asm volatile("s_waitcnt lgkmcnt(0)" ::: "memory");
    __builtin_amdgcn_s_barrier();

#pragma unroll
    for (int kt = 0; kt < 16; kt++) {
        __builtin_amdgcn_sched_barrier(0);
        // issue next B tile then A(kt+2) (oldest-first in vm queue)
        if (kt < 15) {
            STAGE_LOAD_B(breg, (kt + 1) * 64)
        }
        asm volatile("" ::: "memory");  // pin: B-loads before A-loads
        if (kt < 14) {
            LOAD_A_G(aS[kt & 1][0], aS[kt & 1][1], (kt + 2) * 64)
        }
        asm volatile("" ::: "memory");  // close vm issue group

        // compute tile kt from buf kt&1 (A and B both from LDS)
        const unsigned short* Bc = Bl[kt & 1];
        const unsigned short* Ac = Al[kt & 1];
#pragma unroll
        for (int kc = 0; kc < 2; kc++) {
            const int coff = ((kc * 4 + quad) ^ swz) * 8;
            const short8 af = *(const short8*)&Ac[arow * 64 + coff];
#pragma unroll
            for (int n = 0; n < 6; n++) {
                const int row = (g * 6 + n) * 16 + l16;
                const short8 bf = *(const short8*)&Bc[row * 64 + coff];
                acc[n] = __builtin_amdgcn_mfma_f32_16x16x32_bf16(af, bf, acc[n], 0, 0, 0);
            }
        }

        if (kt < 15) {
            // drain A(kt+1)+B(kt+1) for the ds_writes; keep A(kt+2) flying.
            if (kt < 14) {
                asm volatile("s_waitcnt vmcnt(2)" ::: "memory");
            } else {
                asm volatile("s_waitcnt vmcnt(0)" ::: "memory");
            }
            STAGE_WRITE_B((kt + 1) & 1, breg)
            STAGE_WRITE_A((kt + 1) & 1, aS[(kt + 1) & 1][0], aS[(kt + 1) & 1][1])
            asm volatile("s_waitcnt lgkmcnt(0)" ::: "memory");
            __builtin_amdgcn_s_barrier();
        }
    }
#undef STAGE_LOAD_B
#undef STAGE_WRITE_B
#undef LOAD_A_G
#undef STAGE_WRITE_A

    // Epilogue. C layout: row = quad*4 + r, col = l16.
    const int rowD = t0 + rg * 16 + quad * 4;
#pragma unroll
    for (int r = 0; r < 4; r++) {
        const int t = rowD + r;
        const int b = t >> 11, tt = t & 2047;
        if (g == 0) {
#pragma unroll
            for (int n = 0; n < 4; n++)
                ks[(size_t)t * 64 + n * 16 + l16] = f2bf(acc[n][r]);
#pragma unroll
            for (int n = 4; n < 6; n++)
                qs[(size_t)t * 64 + (n - 4) * 16 + l16] = f2bf(acc[n][r] * 0.125f);
        } else {
#pragma unroll
            for (int n = 0; n < 2; n++)
                qs[(size_t)t * 64 + (n + 2) * 16 + l16] = f2bf(acc[n][r] * 0.125f);
#pragma unroll
            for (int n = 2; n < 6; n++)
                vT[(size_t)b * 131072 + (size_t)((n - 2) * 16 + l16) * 2048 + tt] = f2bf(acc[n][r]);
        }
    }
}

// ---------------------------------------------------------------------------
// Kernel 3: causal attention v3 — R11 verbatim (best measured: ~33us)
// ---------------------------------------------------------------------------
__global__ __launch_bounds__(256) void attn_kernel(
    const unsigned short* __restrict__ qs, const unsigned short* __restrict__ ks,
    const unsigned short* __restrict__ vT, float* __restrict__ out) {
    __shared__ unsigned short Kl[4 * 64 * 72];
    __shared__ unsigned short Vl[64 * 264];
    __shared__ unsigned short P[4][16 * 72];
    __shared__ float Ll[4][16];
    float* Of = (float*)Kl;  // merge buffer aliases Kl: [4][16][68] fp32

    const int tid  = threadIdx.x;
    const int lane = tid & 63;
    const int wave = tid >> 6;
    const int quad = lane >> 4;
    const int l16  = lane & 15;
    const int bx   = blockIdx.x;
    const int b    = bx & 7;
    const int i    = bx >> 3;
    const int qt   = (i & 1) ? (127 - (i >> 1)) : (i >> 1);
    const int t0   = qt * 16;

    const unsigned short* qb = qs + (size_t)b * 131072;
    const unsigned short* kb = ks + (size_t)b * 131072;
    const unsigned short* vb = vT + (size_t)b * 131072;

    const int ksr = tid >> 3;
    const int ksc = (tid & 7) * 8;
    const int vsr = tid >> 5;
    const int vsc = (tid & 31) * 8;

    const int qrow = t0 + l16;
    const short8 qf0 = *(const short8*)(qb + (size_t)qrow * 64 + quad * 8);
    const short8 qf1 = *(const short8*)(qb + (size_t)qrow * 64 + 32 + quad * 8);

    float4v o[4];
#pragma unroll
    for (int ot = 0; ot < 4; ot++) o[ot] = (float4v){0.f, 0.f, 0.f, 0.f};
    float lpart = 0.f;

    const int nkb  = (qt >> 2) + 1;
    const int nsup = (nkb + 3) >> 2;

    for (int s = 0; s < nsup; s++) {
        const int key0 = s * 256;
        __syncthreads();
#pragma unroll
        for (int i2 = 0; i2 < 8; i2++) {
            int kr = key0 + i2 * 32 + ksr; kr = kr < 2047 ? kr : 2047;
            *(short8*)&Kl[(i2 * 32 + ksr) * 72 + ksc] = *(const short8*)(kb + (size_t)kr * 64 + ksc);
        }
#pragma unroll
        for (int i2 = 0; i2 < 8; i2++) {
            const int orow = i2 * 8 + vsr;
            int kc2 = key0 + vsc; kc2 = kc2 < 2040 ? kc2 : 2040;
            *(short8*)&Vl[orow * 264 + vsc] = *(const short8*)(vb + (size_t)orow * 2048 + kc2);
        }
        __syncthreads();

        const int jt = s * 4 + wave;
        if (jt < nkb) {
            const int kbase = wave * 64;
            float4v sv[4];
#pragma unroll
            for (int kt = 0; kt < 4; kt++) {
                const short8 ka = *(const short8*)&Kl[(kbase + kt * 16 + l16) * 72 + quad * 8];
                const short8 kc = *(const short8*)&Kl[(kbase + kt * 16 + l16) * 72 + 32 + quad * 8];
                float4v z = (float4v){0.f, 0.f, 0.f, 0.f};
                z = __builtin_amdgcn_mfma_f32_16x16x32_bf16(ka, qf0, z, 0, 0, 0);
                sv[kt] = __builtin_amdgcn_mfma_f32_16x16x32_bf16(kc, qf1, z, 0, 0, 0);
            }
            if (jt == nkb - 1) {
#pragma unroll
                for (int kt = 0; kt < 4; kt++)
#pragma unroll
                    for (int r = 0; r < 4; r++)
                        if (jt * 64 + kt * 16 + quad * 4 + r > qrow) sv[kt][r] = -1e30f;
            }
#pragma unroll
            for (int kt = 0; kt < 4; kt++) {
                float p0 = exp2f(sv[kt][0] * LOG2E);
                float p1 = exp2f(sv[kt][1] * LOG2E);
                float p2 = exp2f(sv[kt][2] * LOG2E);
                float p3 = exp2f(sv[kt][3] * LOG2E);
                lpart += (p0 + p1) + (p2 + p3);
                unsigned int lo = (unsigned int)f2bf(p0) | ((unsigned int)f2bf(p1) << 16);
                unsigned int hi = (unsigned int)f2bf(p2) | ((unsigned int)f2bf(p3) << 16);
                unsigned long long w = ((unsigned long long)hi << 32) | lo;
                *(unsigned long long*)&P[wave][l16 * 72 + kt * 16 + quad * 4] = w;
            }
#pragma unroll
            for (int kc = 0; kc < 2; kc++) {
                const short8 pf = *(const short8*)&P[wave][l16 * 72 + kc * 32 + quad * 8];
#pragma unroll
                for (int ot = 0; ot < 4; ot++) {
                    const short8 vf = *(const short8*)&Vl[(ot * 16 + l16) * 264 + wave * 64 + kc * 32 + quad * 8];
                    o[ot] = __builtin_amdgcn_mfma_f32_16x16x32_bf16(pf, vf, o[ot], 0, 0, 0);
                }
            }
        }
    }

    lpart += __shfl_xor(lpart, 16);
    lpart += __shfl_xor(lpart, 32);
    __syncthreads();
#pragma unroll
    for (int r = 0; r < 4; r++)
#pragma unroll
        for (int ot = 0; ot < 4; ot++)
            Of[wave * 1088 + (quad * 4 + r) * 68 + ot * 16 + l16] = o[ot][r];
    if (lane < 16) Ll[wave][lane] = lpart;
    __syncthreads();

    {
        const int row = tid >> 4;
        const int c0  = (tid & 15) * 4;
        const float lsum = Ll[0][row] + Ll[1][row] + Ll[2][row] + Ll[3][row];
        float4v v0 = *(const float4v*)&Of[0 * 1088 + row * 68 + c0];
        float4v v1 = *(const float4v*)&Of[1 * 1088 + row * 68 + c0];
        float4v v2 = *(const float4v*)&Of[2 * 1088 + row * 68 + c0];
        float4v v3 = *(const float4v*)&Of[3 * 1088 + row * 68 + c0];
        float4v res;
        const float inv = 1.0f / lsum;
#pragma unroll
        for (int j = 0; j < 4; j++)
            res[j] = ((v0[j] + v1[j]) + (v2[j] + v3[j])) * inv;
        float* ob = out + (size_t)b * 131072 + (size_t)(t0 + row) * 64 + c0;
        *(float4v*)ob = res;
    }
}

// ---------------------------------------------------------------------------
extern "C" void kernel_launch(void* const* d_in, const int* in_sizes, int n_in,
                              void* d_out, int out_size, void* d_ws, size_t ws_size,
                              hipStream_t stream) {
    const float* x  = (const float*)d_in[0];
    const float* Wk = (const float*)d_in[1];
    const float* Wq = (const float*)d_in[2];
    const float* Wv = (const float*)d_in[3];
    float* out = (float*)d_out;

    // Workspace: Wb 384 KB (+pad) | qs 2 MB | ks 2 MB | vT 2 MB
    unsigned short* Wb  = (unsigned short*)d_ws;
    unsigned short* qsb = (unsigned short*)((char*)d_ws + 393216);
    unsigned short* ksb = qsb + 1048576;
    unsigned short* vTb = ksb + 1048576;

    hipLaunchKernelGGL(wconv_kernel, dim3(768), dim3(256), 0, stream, Wk, Wq, Wv, Wb);
    hipLaunchKernelGGL(proj_kernel, dim3(512), dim3(256), 0, stream, x, Wb, qsb, ksb, vTb);
    hipLaunchKernelGGL(attn_kernel, dim3(1024), dim3(256), 0, stream, qsb, ksb, vTb, out);
}